// Round 20
// baseline (109.271 us; speedup 1.0000x reference)
//
#include <hip/hip_runtime.h>
#include <hip/hip_bf16.h>

#define HEADS 8
#define HD    32

typedef __attribute__((ext_vector_type(8))) short short8;
typedef __attribute__((ext_vector_type(4))) float f32x4;
typedef __attribute__((ext_vector_type(16))) float f32x16;
typedef unsigned short us;

__device__ __forceinline__ us f2bf(float f) {
  union { __hip_bfloat16 h; us u; } cv;
  cv.h = __float2bfloat16(f);
  return cv.u;
}
__device__ __forceinline__ float bf2f(us u) {
  union { float f; unsigned int i; } cv;
  cv.i = ((unsigned int)u) << 16;
  return cv.f;
}
// native v_exp_f32: computes 2^x (1 trans op; exp2f lib call has slow-path VALU)
__device__ __forceinline__ float exp2_native(float x) {
  float r;
  asm("v_exp_f32 %0, %1" : "=v"(r) : "v"(x));
  return r;
}
// async global->LDS 16B/lane: LDS dest = wave-uniform base + lane*16 (linear);
// swizzle implemented on the per-lane GLOBAL address (guide rule 21).
__device__ __forceinline__ void glds16(const us* g, us* l) {
  __builtin_amdgcn_global_load_lds(
      (const __attribute__((address_space(1))) void*)g,
      (__attribute__((address_space(3))) void*)l, 16, 0, 0);
}

// segment descriptor for merged GEMM launches
struct GP {
  const void* X;      // xmode0: f32 [B][C][N]; xmode2: f32 split-K numerators;
                      // xmode3: f32 high-res [B][C][64][64] (inline 2x2 avgpool)
  const float* den;   // xmode2: denominators [sp][b][h][N] (sp stride 16N)
  const float* W; const float* bias; void* out;
  int C, O, N, omode, xmode, nsp; float alpha;
};

// ---------------------------------------------------------------------------
// MFMA conv-as-GEMM body (split precision, f32-equivalent). XMODE/NSP are
// COMPILE-TIME (R16 lesson). LDS passed in from kernel (R18 lesson: per-
// instantiation __shared__ gets SUMMED -> 96KB -> 1 block/CU).
// ---------------------------------------------------------------------------
template<int XMODE, int NSP>
__device__ __forceinline__ void gemm_body(const GP& g, int bid,
                                          us* Wh, us* Wl, us* Xh, us* Xl) {
  const int C = g.C, O = g.O, N = g.N;
  int nx = N >> 6, nyo = O >> 6;
  int b = bid / (nx * nyo);
  int rr = bid - b * (nx * nyo);
  int o0 = (rr / nx) << 6;
  int n0 = (rr - (rr / nx) * nx) << 6;

  int tid = threadIdx.x, w = tid >> 6, l = tid & 63, lq = l & 15, l4 = l >> 4;

  int wr = tid >> 2, wcb = tid & 3;    // W: row 0..63, 8c-block 0..3
  int xn = tid & 63, xcg = tid >> 6;   // X: n 0..63, 8c-group 0..3
  const float* Wp = g.W + (size_t)(o0 + wr) * C + wcb * 8;
  const float* Xf = (const float*)g.X;
  size_t xbase = (size_t)b * C * N + n0 + xn;
  int wof = wr * 32 + ((wcb ^ ((wr >> 1) & 3)) << 3);
  int xof = xn * 32 + ((xcg ^ ((xn >> 1) & 3)) << 3);

  auto stage = [&](int s, int bufi) {
    int c0 = s << 5;
    float4 wa = *(const float4*)(Wp + c0);
    float4 wb = *(const float4*)(Wp + c0 + 4);
    float wv[8] = {wa.x, wa.y, wa.z, wa.w, wb.x, wb.y, wb.z, wb.w};
    short8 whv, wlv;
#pragma unroll
    for (int j = 0; j < 8; ++j) {
      us h = f2bf(wv[j]);
      whv[j] = (short)h;
      wlv[j] = (short)f2bf(wv[j] - bf2f(h));
    }
    *(short8*)&Wh[bufi * 2048 + wof] = whv;
    *(short8*)&Wl[bufi * 2048 + wof] = wlv;
    float inv = 0.f;
    if constexpr (XMODE == 2) {
      size_t doff = ((size_t)(b * 8 + (c0 >> 5))) * N + n0 + xn;
      float dsum = 0.f;
#pragma unroll
      for (int s2 = 0; s2 < NSP; ++s2) dsum += g.den[(size_t)s2 * 16 * N + doff];
      inv = 1.f / dsum;
    }
    short8 xhv, xlv;
#pragma unroll
    for (int j = 0; j < 8; ++j) {
      int c = c0 + xcg * 8 + j;
      float xv;
      if constexpr (XMODE == 0) {
        xv = Xf[xbase + (size_t)c * N];
      } else if constexpr (XMODE == 2) {
        xv = 0.f;
#pragma unroll
        for (int s2 = 0; s2 < NSP; ++s2)
          xv += Xf[(size_t)s2 * 512 * N + xbase + (size_t)c * N];
        xv *= inv;
      } else {  // XMODE 3: inline 2x2 avgpool from f32 [B][C][64][64]
        int n = n0 + xn, yy = n >> 5, xx = (n & 31) << 1;
        const float* hp = Xf + ((size_t)(b * C + c)) * 4096 + yy * 128 + xx;
        xv = 0.25f * (hp[0] + hp[1] + hp[64] + hp[65]);
      }
      us h = f2bf(xv);
      xhv[j] = (short)h;
      xlv[j] = (short)f2bf(xv - bf2f(h));
    }
    *(short8*)&Xh[bufi * 2048 + xof] = xhv;
    *(short8*)&Xl[bufi * 2048 + xof] = xlv;
  };

  f32x4 acc[4] = {{0,0,0,0},{0,0,0,0},{0,0,0,0},{0,0,0,0}};
  int ns = C >> 5, cur = 0;
  stage(0, 0);
  for (int s = 0; s < ns; ++s) {
    __syncthreads();
    if (s + 1 < ns) stage(s + 1, cur ^ 1);
    int swz = (l4 ^ ((lq >> 1) & 3)) << 3;
    int arow = w * 16 + lq;
    short8 ah = *(const short8*)&Wh[cur * 2048 + arow * 32 + swz];
    short8 al = *(const short8*)&Wl[cur * 2048 + arow * 32 + swz];
    __builtin_amdgcn_s_setprio(1);
#pragma unroll
    for (int nf = 0; nf < 4; ++nf) {
      int brow = nf * 16 + lq;
      short8 bh = *(const short8*)&Xh[cur * 2048 + brow * 32 + swz];
      short8 bl = *(const short8*)&Xl[cur * 2048 + brow * 32 + swz];
      acc[nf] = __builtin_amdgcn_mfma_f32_16x16x32_bf16(ah, bh, acc[nf], 0, 0, 0);
      acc[nf] = __builtin_amdgcn_mfma_f32_16x16x32_bf16(ah, bl, acc[nf], 0, 0, 0);
      acc[nf] = __builtin_amdgcn_mfma_f32_16x16x32_bf16(al, bh, acc[nf], 0, 0, 0);
    }
    __builtin_amdgcn_s_setprio(0);
    cur ^= 1;
  }

  float bv[4];
#pragma unroll
  for (int r = 0; r < 4; ++r) bv[r] = g.bias[o0 + w * 16 + l4 * 4 + r];
  if (g.omode == 0) {
    us* ob = (us*)g.out;
#pragma unroll
    for (int nf = 0; nf < 4; ++nf) {
      ushort4 pk;
      pk.x = f2bf((acc[nf][0] + bv[0]) * g.alpha);
      pk.y = f2bf((acc[nf][1] + bv[1]) * g.alpha);
      pk.z = f2bf((acc[nf][2] + bv[2]) * g.alpha);
      pk.w = f2bf((acc[nf][3] + bv[3]) * g.alpha);
      *(ushort4*)&ob[((size_t)b * N + n0 + nf * 16 + lq) * O + o0 + w * 16 + l4 * 4] = pk;
    }
  } else if (g.omode == 1) {
    us* ob = (us*)g.out;
#pragma unroll
    for (int nf = 0; nf < 4; ++nf)
#pragma unroll
      for (int r = 0; r < 4; ++r)
        ob[((size_t)(b * O + o0 + w * 16 + l4 * 4 + r)) * N + n0 + nf * 16 + lq] =
            f2bf(acc[nf][r] + bv[r]);
  } else {
    float* of = (float*)g.out;
#pragma unroll
    for (int nf = 0; nf < 4; ++nf)
#pragma unroll
      for (int r = 0; r < 4; ++r)
        of[((size_t)(b * O + o0 + w * 16 + l4 * 4 + r)) * N + n0 + nf * 16 + lq] =
            acc[nf][r] + bv[r];
  }
}

__global__ __launch_bounds__(256) void gemm_conv(
    GP g0, GP g1, GP g2, GP g3, GP g4, GP g5,
    int nb0, int nb1, int nb2, int nb3, int nb4) {
  // ONE shared allocation for all template instantiations (32 KB total)
  __shared__ __align__(16) us Wh[2 * 2048], Wl[2 * 2048];
  __shared__ __align__(16) us Xh[2 * 2048], Xl[2 * 2048];
  int bid = blockIdx.x;
  GP g;
  if (bid < nb0) g = g0;
  else if (bid < nb0 + nb1) { g = g1; bid -= nb0; }
  else if (bid < nb0 + nb1 + nb2) { g = g2; bid -= nb0 + nb1; }
  else if (bid < nb0 + nb1 + nb2 + nb3) { g = g3; bid -= nb0 + nb1 + nb2; }
  else if (bid < nb0 + nb1 + nb2 + nb3 + nb4) { g = g4; bid -= nb0 + nb1 + nb2 + nb3; }
  else { g = g5; bid -= nb0 + nb1 + nb2 + nb3 + nb4; }
  if (g.xmode == 0)      gemm_body<0, 1>(g, bid, Wh, Wl, Xh, Xl);
  else if (g.xmode == 3) gemm_body<3, 1>(g, bid, Wh, Wl, Xh, Xl);
  else                   gemm_body<2, 2>(g, bid, Wh, Wl, Xh, Xl);
}

// ---------------------------------------------------------------------------
// fused bilinear 2x upsamples (unchanged)
// ---------------------------------------------------------------------------
__global__ __launch_bounds__(256) void upsample_both(
    const us* __restrict__ inT, us* __restrict__ outT,
    const us* __restrict__ inC, us* __restrict__ outC, int nbT, int BC) {
  if ((int)blockIdx.x < nbT) {
    int rowg = blockIdx.x * 4 + (threadIdx.x >> 6);
    int ch = (threadIdx.x & 63) * 4;
    int b = rowg >> 12, n = rowg & 4095;
    int y = n >> 6, x = n & 63;
    float sy = y * 0.5f - 0.25f, sx = x * 0.5f - 0.25f;
    int y0 = (int)floorf(sy), x0 = (int)floorf(sx);
    float fy = sy - (float)y0, fx = sx - (float)x0;
    int y0c = max(y0, 0), y1c = min(y0 + 1, 31);
    int x0c = max(x0, 0), x1c = min(x0 + 1, 31);
    const us* ip = inT + (size_t)b * 1024 * 256 + ch;
    ushort4 v00 = *(const ushort4*)&ip[(size_t)(y0c * 32 + x0c) * 256];
    ushort4 v01 = *(const ushort4*)&ip[(size_t)(y0c * 32 + x1c) * 256];
    ushort4 v10 = *(const ushort4*)&ip[(size_t)(y1c * 32 + x0c) * 256];
    ushort4 v11 = *(const ushort4*)&ip[(size_t)(y1c * 32 + x1c) * 256];
    float w00 = (1.f - fy) * (1.f - fx), w01 = (1.f - fy) * fx;
    float w10 = fy * (1.f - fx), w11 = fy * fx;
    ushort4 o;
    o.x = f2bf(w00 * bf2f(v00.x) + w01 * bf2f(v01.x) + w10 * bf2f(v10.x) + w11 * bf2f(v11.x));
    o.y = f2bf(w00 * bf2f(v00.y) + w01 * bf2f(v01.y) + w10 * bf2f(v10.y) + w11 * bf2f(v11.y));
    o.z = f2bf(w00 * bf2f(v00.z) + w01 * bf2f(v01.z) + w10 * bf2f(v10.z) + w11 * bf2f(v11.z));
    o.w = f2bf(w00 * bf2f(v00.w) + w01 * bf2f(v01.w) + w10 * bf2f(v10.w) + w11 * bf2f(v11.w));
    *(ushort4*)&outT[((size_t)b * 4096 + n) * 256 + ch] = o;
  } else {
    int t = ((int)blockIdx.x - nbT) * 256 + threadIdx.x;
    if (t >= BC * 64) return;
    int y = t & 63, bc = t >> 6;
    float sy = y * 0.5f - 0.25f;
    int y0 = (int)floorf(sy);
    float fy = sy - (float)y0;
    int y0c = max(y0, 0), y1c = min(y0 + 1, 31);
    const us* r0 = inC + (size_t)bc * 1024 + y0c * 32;
    const us* r1 = inC + (size_t)bc * 1024 + y1c * 32;
    float m[32];
#pragma unroll
    for (int j = 0; j < 32; j += 8) {
      short8 a = *(const short8*)(r0 + j);
      short8 c = *(const short8*)(r1 + j);
#pragma unroll
      for (int e = 0; e < 8; ++e)
        m[j + e] = (1.f - fy) * bf2f((us)a[e]) + fy * bf2f((us)c[e]);
    }
    us* op = outC + (size_t)bc * 4096 + y * 64;
    short8 o8;
#pragma unroll
    for (int xo = 0; xo < 64; ++xo) {
      int k = xo >> 1;
      float v;
      if (xo & 1) v = (k < 31) ? 0.75f * m[k] + 0.25f * m[k + 1] : m[31];
      else        v = (k > 0) ? 0.25f * m[k - 1] + 0.75f * m[k] : m[0];
      o8[xo & 7] = (short)f2bf(v);
      if ((xo & 7) == 7) *(short8*)(op + (xo & ~7)) = o8;
    }
  }
}

// ---------------------------------------------------------------------------
// MFMA flash attention, 32x32x16 shape, ZERO-LDS P hand-off via
// v_permlane32_swap (the 32x32 C/D layout makes the P redistribution an
// exact lane<32 <-> lane>=32 half-exchange). Split-K x2 (exact, max-free
// softmax). K/V staging, swizzles, XCD map unchanged from R19.
// Block = 4 waves x 32 q = 128 q. LDS = 16 KB (Pt eliminated).
// ---------------------------------------------------------------------------
__global__ __launch_bounds__(256) void attn_mfma(
    const us* __restrict__ qT0, const us* __restrict__ kT0,
    const us* __restrict__ vC0, float* __restrict__ pn0, float* __restrict__ pd0,
    int N0, int nb0, int nsp0,
    const us* __restrict__ qT1, const us* __restrict__ kT1,
    const us* __restrict__ vC1, float* __restrict__ pn1, float* __restrict__ pd1,
    int N1, int nsp1) {
  __shared__ __align__(16) us Kt[2][64 * 32];   // [key][d] (src-swizzled)
  __shared__ __align__(16) us Vt[2][32 * 64];   // [d][key] (src-swizzled)

  int bid = blockIdx.x;
  const us *qT, *kT, *vC; float *pn, *pd; int N, nsp;
  if (bid < nb0) {
    qT = qT0; kT = kT0; vC = vC0; pn = pn0; pd = pd0; N = N0; nsp = nsp0;
  } else {
    bid -= nb0;
    qT = qT1; kT = kT1; vC = vC1; pn = pn1; pd = pd1; N = N1; nsp = nsp1;
  }
  int xcd = bid & 7, slot = bid >> 3;
  int nqb = N >> 7, per = nqb * nsp;
  int qs = slot % per;
  int bh = ((slot / per) << 3) | xcd;    // head pinned to XCD
  int qb = qs / nsp, sp = qs % nsp;
  int b = bh >> 3, h = bh & 7;
  int SK = N / nsp;                      // keys per split
  int tid = threadIdx.x;
  int w = tid >> 6, l = tid & 63;
  int q5 = l & 31, hi = l >> 5;

  // Q B-frags: B[k=hi*8+j][col=q5]; qf0 for d=0..15, qf1 for d=16..31
  short8 qf0, qf1;
  {
    const us* qp = qT + ((size_t)(b * N + qb * 128 + w * 32 + q5)) * 256 +
                   h * 32 + hi * 8;
    qf0 = *(const short8*)qp;
    qf1 = *(const short8*)(qp + 16);
  }

  // --- staging: per-lane swizzled GLOBAL pointers (+ split key offset) ---
  int rK = w * 16 + (l >> 2);
  const us* gK = kT + ((size_t)(b * N + sp * SK + rK)) * 256 + h * 32 +
                 (((l & 3) ^ ((rK >> 1) & 3)) << 3);
  int dV = w * 8 + (l >> 3);
  const us* gV = vC + ((size_t)(b * 256 + h * 32 + dV)) * N + sp * SK +
                 (((l & 7) ^ (dV & 7)) << 3);

  f32x16 acc = {0.f};    // out^T[d][q]: col=q5, row d=(reg&3)+8*(reg>>2)+4*hi
  f32x16 accD = {0.f};   // ones-row denominator (all rows equal)
  short8 ones;
#pragma unroll
  for (int j = 0; j < 8; ++j) ones[j] = (short)0x3F80;   // bf16 1.0

  // prologue: stage tile 0 into buf 0 (async; first barrier drains)
  glds16(gK, &Kt[0][w * 512]);
  glds16(gV, &Vt[0][w * 512]);

  int nt = SK >> 6, cur = 0;
  for (int t = 0; t < nt; ++t) {
    __syncthreads();                       // drains glds: buf[cur] ready
    if (t + 1 < nt) {                      // issue next tile early (T14)
      glds16(gK + (size_t)(t + 1) * 64 * 256, &Kt[cur ^ 1][w * 512]);
      glds16(gV + (t + 1) * 64, &Vt[cur ^ 1][w * 512]);
    }
    const us* Kb = Kt[cur];
    const us* Vb = Vt[cur];

#pragma unroll
    for (int grp = 0; grp < 2; ++grp) {    // two 32-key groups per tile
      // --- QK^T: S^T[key][q], A=K (row=key=q5-in-group), B=Q; chain d-halves
      int kr = grp * 32 + q5;
      short8 ka = *(const short8*)&Kb[kr * 32 + ((hi ^ ((kr >> 1) & 3)) << 3)];
      short8 kb2 = *(const short8*)&Kb[kr * 32 + (((2 + hi) ^ ((kr >> 1) & 3)) << 3)];
      f32x16 s = {0.f};
      __builtin_amdgcn_s_setprio(1);
      s = __builtin_amdgcn_mfma_f32_32x32x16_bf16(ka, qf0, s, 0, 0, 0);
      s = __builtin_amdgcn_mfma_f32_32x32x16_bf16(kb2, qf1, s, 0, 0, 0);
      __builtin_amdgcn_s_setprio(0);

      // --- softmax numerator: p[r] for key=(r&3)+8*(r>>2)+4*hi (within group)
      unsigned int u[8];
#pragma unroll
      for (int i = 0; i < 8; ++i) {
        float pa = exp2_native(s[2 * i]);
        float pb = exp2_native(s[2 * i + 1]);
        asm("v_cvt_pk_bf16_f32 %0, %1, %2" : "=v"(u[i]) : "v"(pa), "v"(pb));
      }
      // u0=(keys 4hi+0,1) u1=(4hi+2,3) u2=(8+4hi+0,1) u3=(8+4hi+2,3)
      // u4..u7 same for keys 16..31 of the group.
      // permlane32_swap: B-frags for the two k=16 PV MFMAs (zero LDS).
      asm volatile("v_permlane32_swap_b32 %0, %1" : "+v"(u[0]), "+v"(u[2]));
      asm volatile("v_permlane32_swap_b32 %0, %1" : "+v"(u[1]), "+v"(u[3]));
      asm volatile("v_permlane32_swap_b32 %0, %1" : "+v"(u[4]), "+v"(u[6]));
      asm volatile("v_permlane32_swap_b32 %0, %1" : "+v"(u[5]), "+v"(u[7]));
      // pfA: keys grp*32+0..15 -> {u0,u1,u2,u3}; pfB: keys 16..31 -> {u4..u7}
      short8 pfA, pfB;
      {
        union { unsigned int w2[4]; short8 s8; } cvA, cvB;
        cvA.w2[0] = u[0]; cvA.w2[1] = u[1]; cvA.w2[2] = u[2]; cvA.w2[3] = u[3];
        cvB.w2[0] = u[4]; cvB.w2[1] = u[5]; cvB.w2[2] = u[6]; cvB.w2[3] = u[7];
        pfA = cvA.s8; pfB = cvB.s8;
      }

      // --- PV + ones-denominator: A=V^T[d=q5][key], 1 b128 per k16 MFMA
      int kb0 = grp * 4 + hi;        // key-block (8 keys) for keys 0..15
      int kb1 = grp * 4 + 2 + hi;    // for keys 16..31
      short8 va = *(const short8*)&Vb[q5 * 64 + ((kb0 ^ (q5 & 7)) << 3)];
      short8 vb = *(const short8*)&Vb[q5 * 64 + ((kb1 ^ (q5 & 7)) << 3)];
      __builtin_amdgcn_s_setprio(1);
      acc  = __builtin_amdgcn_mfma_f32_32x32x16_bf16(va, pfA, acc, 0, 0, 0);
      accD = __builtin_amdgcn_mfma_f32_32x32x16_bf16(ones, pfA, accD, 0, 0, 0);
      acc  = __builtin_amdgcn_mfma_f32_32x32x16_bf16(vb, pfB, acc, 0, 0, 0);
      accD = __builtin_amdgcn_mfma_f32_32x32x16_bf16(ones, pfB, accD, 0, 0, 0);
      __builtin_amdgcn_s_setprio(0);
    }
    cur ^= 1;
  }

  // epilogue: f32 partials. pn[s][b][h][d(32)][N] (s stride 512N), pd[s][b][h][N]
  size_t nbase = ((size_t)((sp * 2 + b) * 8 + h)) * 32 * N;
  size_t dbase = ((size_t)((sp * 2 + b) * 8 + h)) * N;
  int qg = qb * 128 + w * 32 + q5;
#pragma unroll
  for (int r = 0; r < 16; ++r) {
    int d = (r & 3) + 8 * (r >> 2) + 4 * hi;
    pn[nbase + (size_t)d * N + qg] = acc[r];
  }
  if (hi == 0) pd[dbase + qg] = accD[0];
}

// ---------------------------------------------------------------------------
extern "C" void kernel_launch(void* const* d_in, const int* in_sizes, int n_in,
                              void* d_out, int out_size, void* d_ws, size_t ws_size,
                              hipStream_t stream) {
  const float* high_feat  = (const float*)d_in[0];   // [2,128,64,64]
  const float* low_feat   = (const float*)d_in[1];   // [2,256,32,32]
  const float* q_high_w   = (const float*)d_in[2];
  const float* q_high_b   = (const float*)d_in[3];
  const float* k_high_w   = (const float*)d_in[4];
  const float* k_high_b   = (const float*)d_in[5];
  const float* v_high_w   = (const float*)d_in[6];
  const float* v_high_b   = (const float*)d_in[7];
  const float* q_low_w    = (const float*)d_in[8];
  const float* q_low_b    = (const float*)d_in[9];
  const float* k_low_w    = (const float*)d_in[10];
  const float* k_low_b    = (const float*)d_in[11];
  const float* v_low_w    = (const float*)d_in[12];
  const float* v_low_b    = (const float*)d_in[13];
  const float* out_high_w = (const float*)d_in[14];
  const float* out_high_b = (const float*)d_in[15];
  const float* out_low_w  = (const float*)d_in[16];
  const float* out_low_b  = (const float*)d_in[17];

  const int B = 2, Nh = 4096, Nl = 1024;
  const float qa = 0.17677669529663689f * 1.4426950408889634f;  // scale * log2e

  // workspace carve-up (bytes), ~40 MB
  char* p = (char*)d_ws;
  us* qT    = (us*)p; p += (size_t)2 * 4096 * 256 * 2;  // 4MB
  us* kTb   = (us*)p; p += (size_t)2 * 4096 * 256 * 2;  // 4MB
  us* vCb   = (us*)p; p += (size_t)2 * 256 * 4096 * 2;  // 4MB
  us* klbT  = (us*)p; p += (size_t)2 * 1024 * 256 * 2;  // 1MB
  us* vlb   = (us*)p; p += (size_t)2 * 256 * 1024 * 2;  // 1MB
  us* qTl   = (us*)p; p += (size_t)2 * 1024 * 256 * 2;  // 1MB
  us* kTl   = (us*)p; p += (size_t)2 * 1024 * 256 * 2;  // 1MB
  us* vCl   = (us*)p; p += (size_t)2 * 256 * 1024 * 2;  // 1MB
  float* pnH = (float*)p; p += (size_t)2 * 16 * 32 * 4096 * 4;  // 16.8MB (2 splits)
  float* pdH = (float*)p; p += (size_t)2 * 16 * 4096 * 4;       // 0.5MB
  float* pnL = (float*)p; p += (size_t)2 * 16 * 32 * 1024 * 4;  // 4.2MB (2 splits)
  float* pdL = (float*)p; p += (size_t)2 * 16 * 1024 * 4;       // 0.13MB

  float* out_high = (float*)d_out;             // [2][128][4096]
  float* out_low  = out_high + 2 * 128 * 4096; // [2][256][1024]

  GP z = {nullptr, nullptr, nullptr, nullptr, nullptr, 32, 64, 64, 2, 0, 1, 0.f};

  // 1. ALL input-side GEMMs in ONE launch (k_high/v_high avgpool inline)
  {
    GP s0 = {low_feat,  nullptr, k_low_w,  k_low_b,  klbT, 256, 256, Nl, 0, 0, 1, 1.0f};  // 128
    GP s1 = {low_feat,  nullptr, v_low_w,  v_low_b,  vlb,  256, 256, Nl, 1, 0, 1, 1.0f};  // 128
    GP s2 = {high_feat, nullptr, q_high_w, q_high_b, qT,   128, 256, Nh, 0, 0, 1, qa};    // 512
    GP s3 = {low_feat,  nullptr, q_low_w,  q_low_b,  qTl,  256, 256, Nl, 0, 0, 1, qa};    // 128
    GP s4 = {high_feat, nullptr, k_high_w, k_high_b, kTl,  128, 256, Nl, 0, 3, 1, 1.0f};  // 128
    GP s5 = {high_feat, nullptr, v_high_w, v_high_b, vCl,  128, 256, Nl, 1, 3, 1, 1.0f};  // 128
    gemm_conv<<<1152, 256, 0, stream>>>(s0, s1, s2, s3, s4, s5, 128, 128, 512, 128, 128);
  }
  // 2. both upsamples in ONE launch
  upsample_both<<<2048 + 128, 256, 0, stream>>>(klbT, kTb, vlb, vCb, 2048, B * 256);
  // 3. attention: high split-K x2 (1024 blocks) + low x2 (256), XCD-mapped
  {
    int nb0 = 16 * (Nh / 128) * 2, nb1 = 16 * (Nl / 128) * 2;
    attn_mfma<<<nb0 + nb1, 256, 0, stream>>>(
        qT, kTb, vCb, pnH, pdH, Nh, nb0, 2,
        qTl, kTl, vCl, pnL, pdL, Nl, 2);
  }
  // 4. both output convs in ONE launch, split-K reduce FUSED into staging
  {
    GP s0 = {pnH, pdH, out_high_w, out_high_b, out_high, 256, 128, Nh, 2, 2, 2, 1.0f};  // 256
    GP s1 = {pnL, pdL, out_low_w,  out_low_b,  out_low,  256, 256, Nl, 2, 2, 2, 1.0f};  // 128
    gemm_conv<<<384, 256, 0, stream>>>(s0, s1, z, z, z, z, 256, 128, 0, 0, 0);
  }
}

// Round 21
// 101.858 us; speedup vs baseline: 1.0728x; 1.0728x over previous
//
#include <hip/hip_runtime.h>
#include <hip/hip_bf16.h>

#define HEADS 8
#define HD    32

typedef __attribute__((ext_vector_type(8))) short short8;
typedef __attribute__((ext_vector_type(4))) float f32x4;
typedef unsigned short us;

__device__ __forceinline__ us f2bf(float f) {
  union { __hip_bfloat16 h; us u; } cv;
  cv.h = __float2bfloat16(f);
  return cv.u;
}
__device__ __forceinline__ float bf2f(us u) {
  union { float f; unsigned int i; } cv;
  cv.i = ((unsigned int)u) << 16;
  return cv.f;
}
// native v_exp_f32: computes 2^x (1 trans op; exp2f lib call has slow-path VALU)
__device__ __forceinline__ float exp2_native(float x) {
  float r;
  asm("v_exp_f32 %0, %1" : "=v"(r) : "v"(x));
  return r;
}
// async global->LDS 16B/lane: LDS dest = wave-uniform base + lane*16 (linear);
// swizzle implemented on the per-lane GLOBAL address (guide rule 21).
__device__ __forceinline__ void glds16(const us* g, us* l) {
  __builtin_amdgcn_global_load_lds(
      (const __attribute__((address_space(1))) void*)g,
      (__attribute__((address_space(3))) void*)l, 16, 0, 0);
}

// segment descriptor for merged GEMM launches
struct GP {
  const void* X;      // xmode0: f32 [B][C][N]; xmode2: f32 split-K numerators;
                      // xmode3: f32 high-res [B][C][64][64] (inline 2x2 avgpool)
  const float* den;   // xmode2: denominators [sp][b][h][N] (sp stride 16N)
  const float* W; const float* bias; void* out;
  int C, O, N, omode, xmode, nsp; float alpha;
};

// ---------------------------------------------------------------------------
// MFMA conv-as-GEMM body (split precision, f32-equivalent). XMODE/NSP are
// COMPILE-TIME (R16 lesson). LDS passed in from kernel (R18 lesson: per-
// instantiation __shared__ gets SUMMED -> 96KB -> 1 block/CU).
// ---------------------------------------------------------------------------
template<int XMODE, int NSP>
__device__ __forceinline__ void gemm_body(const GP& g, int bid,
                                          us* Wh, us* Wl, us* Xh, us* Xl) {
  const int C = g.C, O = g.O, N = g.N;
  int nx = N >> 6, nyo = O >> 6;
  int b = bid / (nx * nyo);
  int rr = bid - b * (nx * nyo);
  int o0 = (rr / nx) << 6;
  int n0 = (rr - (rr / nx) * nx) << 6;

  int tid = threadIdx.x, w = tid >> 6, l = tid & 63, lq = l & 15, l4 = l >> 4;

  int wr = tid >> 2, wcb = tid & 3;    // W: row 0..63, 8c-block 0..3
  int xn = tid & 63, xcg = tid >> 6;   // X: n 0..63, 8c-group 0..3
  const float* Wp = g.W + (size_t)(o0 + wr) * C + wcb * 8;
  const float* Xf = (const float*)g.X;
  size_t xbase = (size_t)b * C * N + n0 + xn;
  int wof = wr * 32 + ((wcb ^ ((wr >> 1) & 3)) << 3);
  int xof = xn * 32 + ((xcg ^ ((xn >> 1) & 3)) << 3);

  auto stage = [&](int s, int bufi) {
    int c0 = s << 5;
    float4 wa = *(const float4*)(Wp + c0);
    float4 wb = *(const float4*)(Wp + c0 + 4);
    float wv[8] = {wa.x, wa.y, wa.z, wa.w, wb.x, wb.y, wb.z, wb.w};
    short8 whv, wlv;
#pragma unroll
    for (int j = 0; j < 8; ++j) {
      us h = f2bf(wv[j]);
      whv[j] = (short)h;
      wlv[j] = (short)f2bf(wv[j] - bf2f(h));
    }
    *(short8*)&Wh[bufi * 2048 + wof] = whv;
    *(short8*)&Wl[bufi * 2048 + wof] = wlv;
    float inv = 0.f;
    if constexpr (XMODE == 2) {
      size_t doff = ((size_t)(b * 8 + (c0 >> 5))) * N + n0 + xn;
      float dsum = 0.f;
#pragma unroll
      for (int s2 = 0; s2 < NSP; ++s2) dsum += g.den[(size_t)s2 * 16 * N + doff];
      inv = 1.f / dsum;
    }
    short8 xhv, xlv;
#pragma unroll
    for (int j = 0; j < 8; ++j) {
      int c = c0 + xcg * 8 + j;
      float xv;
      if constexpr (XMODE == 0) {
        xv = Xf[xbase + (size_t)c * N];
      } else if constexpr (XMODE == 2) {
        xv = 0.f;
#pragma unroll
        for (int s2 = 0; s2 < NSP; ++s2)
          xv += Xf[(size_t)s2 * 512 * N + xbase + (size_t)c * N];
        xv *= inv;
      } else {  // XMODE 3: inline 2x2 avgpool from f32 [B][C][64][64]
        int n = n0 + xn, yy = n >> 5, xx = (n & 31) << 1;
        const float* hp = Xf + ((size_t)(b * C + c)) * 4096 + yy * 128 + xx;
        xv = 0.25f * (hp[0] + hp[1] + hp[64] + hp[65]);
      }
      us h = f2bf(xv);
      xhv[j] = (short)h;
      xlv[j] = (short)f2bf(xv - bf2f(h));
    }
    *(short8*)&Xh[bufi * 2048 + xof] = xhv;
    *(short8*)&Xl[bufi * 2048 + xof] = xlv;
  };

  f32x4 acc[4] = {{0,0,0,0},{0,0,0,0},{0,0,0,0},{0,0,0,0}};
  int ns = C >> 5, cur = 0;
  stage(0, 0);
  for (int s = 0; s < ns; ++s) {
    __syncthreads();
    if (s + 1 < ns) stage(s + 1, cur ^ 1);
    int swz = (l4 ^ ((lq >> 1) & 3)) << 3;
    int arow = w * 16 + lq;
    short8 ah = *(const short8*)&Wh[cur * 2048 + arow * 32 + swz];
    short8 al = *(const short8*)&Wl[cur * 2048 + arow * 32 + swz];
    __builtin_amdgcn_s_setprio(1);
#pragma unroll
    for (int nf = 0; nf < 4; ++nf) {
      int brow = nf * 16 + lq;
      short8 bh = *(const short8*)&Xh[cur * 2048 + brow * 32 + swz];
      short8 bl = *(const short8*)&Xl[cur * 2048 + brow * 32 + swz];
      acc[nf] = __builtin_amdgcn_mfma_f32_16x16x32_bf16(ah, bh, acc[nf], 0, 0, 0);
      acc[nf] = __builtin_amdgcn_mfma_f32_16x16x32_bf16(ah, bl, acc[nf], 0, 0, 0);
      acc[nf] = __builtin_amdgcn_mfma_f32_16x16x32_bf16(al, bh, acc[nf], 0, 0, 0);
    }
    __builtin_amdgcn_s_setprio(0);
    cur ^= 1;
  }

  float bv[4];
#pragma unroll
  for (int r = 0; r < 4; ++r) bv[r] = g.bias[o0 + w * 16 + l4 * 4 + r];
  if (g.omode == 0) {
    us* ob = (us*)g.out;
#pragma unroll
    for (int nf = 0; nf < 4; ++nf) {
      ushort4 pk;
      pk.x = f2bf((acc[nf][0] + bv[0]) * g.alpha);
      pk.y = f2bf((acc[nf][1] + bv[1]) * g.alpha);
      pk.z = f2bf((acc[nf][2] + bv[2]) * g.alpha);
      pk.w = f2bf((acc[nf][3] + bv[3]) * g.alpha);
      *(ushort4*)&ob[((size_t)b * N + n0 + nf * 16 + lq) * O + o0 + w * 16 + l4 * 4] = pk;
    }
  } else if (g.omode == 1) {
    us* ob = (us*)g.out;
#pragma unroll
    for (int nf = 0; nf < 4; ++nf)
#pragma unroll
      for (int r = 0; r < 4; ++r)
        ob[((size_t)(b * O + o0 + w * 16 + l4 * 4 + r)) * N + n0 + nf * 16 + lq] =
            f2bf(acc[nf][r] + bv[r]);
  } else {
    float* of = (float*)g.out;
#pragma unroll
    for (int nf = 0; nf < 4; ++nf)
#pragma unroll
      for (int r = 0; r < 4; ++r)
        of[((size_t)(b * O + o0 + w * 16 + l4 * 4 + r)) * N + n0 + nf * 16 + lq] =
            acc[nf][r] + bv[r];
  }
}

__global__ __launch_bounds__(256) void gemm_conv(
    GP g0, GP g1, GP g2, GP g3, GP g4, GP g5,
    int nb0, int nb1, int nb2, int nb3, int nb4) {
  // ONE shared allocation for all template instantiations (32 KB total)
  __shared__ __align__(16) us Wh[2 * 2048], Wl[2 * 2048];
  __shared__ __align__(16) us Xh[2 * 2048], Xl[2 * 2048];
  int bid = blockIdx.x;
  GP g;
  if (bid < nb0) g = g0;
  else if (bid < nb0 + nb1) { g = g1; bid -= nb0; }
  else if (bid < nb0 + nb1 + nb2) { g = g2; bid -= nb0 + nb1; }
  else if (bid < nb0 + nb1 + nb2 + nb3) { g = g3; bid -= nb0 + nb1 + nb2; }
  else if (bid < nb0 + nb1 + nb2 + nb3 + nb4) { g = g4; bid -= nb0 + nb1 + nb2 + nb3; }
  else { g = g5; bid -= nb0 + nb1 + nb2 + nb3 + nb4; }
  if (g.xmode == 0)      gemm_body<0, 1>(g, bid, Wh, Wl, Xh, Xl);
  else if (g.xmode == 3) gemm_body<3, 1>(g, bid, Wh, Wl, Xh, Xl);
  else                   gemm_body<2, 2>(g, bid, Wh, Wl, Xh, Xl);
}

// ---------------------------------------------------------------------------
// fused bilinear 2x upsamples (unchanged)
// ---------------------------------------------------------------------------
__global__ __launch_bounds__(256) void upsample_both(
    const us* __restrict__ inT, us* __restrict__ outT,
    const us* __restrict__ inC, us* __restrict__ outC, int nbT, int BC) {
  if ((int)blockIdx.x < nbT) {
    int rowg = blockIdx.x * 4 + (threadIdx.x >> 6);
    int ch = (threadIdx.x & 63) * 4;
    int b = rowg >> 12, n = rowg & 4095;
    int y = n >> 6, x = n & 63;
    float sy = y * 0.5f - 0.25f, sx = x * 0.5f - 0.25f;
    int y0 = (int)floorf(sy), x0 = (int)floorf(sx);
    float fy = sy - (float)y0, fx = sx - (float)x0;
    int y0c = max(y0, 0), y1c = min(y0 + 1, 31);
    int x0c = max(x0, 0), x1c = min(x0 + 1, 31);
    const us* ip = inT + (size_t)b * 1024 * 256 + ch;
    ushort4 v00 = *(const ushort4*)&ip[(size_t)(y0c * 32 + x0c) * 256];
    ushort4 v01 = *(const ushort4*)&ip[(size_t)(y0c * 32 + x1c) * 256];
    ushort4 v10 = *(const ushort4*)&ip[(size_t)(y1c * 32 + x0c) * 256];
    ushort4 v11 = *(const ushort4*)&ip[(size_t)(y1c * 32 + x1c) * 256];
    float w00 = (1.f - fy) * (1.f - fx), w01 = (1.f - fy) * fx;
    float w10 = fy * (1.f - fx), w11 = fy * fx;
    ushort4 o;
    o.x = f2bf(w00 * bf2f(v00.x) + w01 * bf2f(v01.x) + w10 * bf2f(v10.x) + w11 * bf2f(v11.x));
    o.y = f2bf(w00 * bf2f(v00.y) + w01 * bf2f(v01.y) + w10 * bf2f(v10.y) + w11 * bf2f(v11.y));
    o.z = f2bf(w00 * bf2f(v00.z) + w01 * bf2f(v01.z) + w10 * bf2f(v10.z) + w11 * bf2f(v11.z));
    o.w = f2bf(w00 * bf2f(v00.w) + w01 * bf2f(v01.w) + w10 * bf2f(v10.w) + w11 * bf2f(v11.w));
    *(ushort4*)&outT[((size_t)b * 4096 + n) * 256 + ch] = o;
  } else {
    int t = ((int)blockIdx.x - nbT) * 256 + threadIdx.x;
    if (t >= BC * 64) return;
    int y = t & 63, bc = t >> 6;
    float sy = y * 0.5f - 0.25f;
    int y0 = (int)floorf(sy);
    float fy = sy - (float)y0;
    int y0c = max(y0, 0), y1c = min(y0 + 1, 31);
    const us* r0 = inC + (size_t)bc * 1024 + y0c * 32;
    const us* r1 = inC + (size_t)bc * 1024 + y1c * 32;
    float m[32];
#pragma unroll
    for (int j = 0; j < 32; j += 8) {
      short8 a = *(const short8*)(r0 + j);
      short8 c = *(const short8*)(r1 + j);
#pragma unroll
      for (int e = 0; e < 8; ++e)
        m[j + e] = (1.f - fy) * bf2f((us)a[e]) + fy * bf2f((us)c[e]);
    }
    us* op = outC + (size_t)bc * 4096 + y * 64;
    short8 o8;
#pragma unroll
    for (int xo = 0; xo < 64; ++xo) {
      int k = xo >> 1;
      float v;
      if (xo & 1) v = (k < 31) ? 0.75f * m[k] + 0.25f * m[k + 1] : m[31];
      else        v = (k > 0) ? 0.25f * m[k - 1] + 0.75f * m[k] : m[0];
      o8[xo & 7] = (short)f2bf(v);
      if ((xo & 7) == 7) *(short8*)(op + (xo & ~7)) = o8;
    }
  }
}

// ---------------------------------------------------------------------------
// MFMA flash attention (R19-verified, 69.7us): 16x16x32 shape, split-K x2
// (exact: max-free softmax sums combine additively), 32q/wave K/V-read
// sharing, glds staging (linear LDS, source-swizzled), ones-MFMA
// denominator, native v_exp, cvt_pk, XCD map (bid&7 == bh&7).
// ---------------------------------------------------------------------------
__global__ __launch_bounds__(256) void attn_mfma(
    const us* __restrict__ qT0, const us* __restrict__ kT0,
    const us* __restrict__ vC0, float* __restrict__ pn0, float* __restrict__ pd0,
    int N0, int nb0, int nsp0,
    const us* __restrict__ qT1, const us* __restrict__ kT1,
    const us* __restrict__ vC1, float* __restrict__ pn1, float* __restrict__ pd1,
    int N1, int nsp1) {
  __shared__ __align__(16) us Kt[2][64 * 32];   // [key][d] (src-swizzled)
  __shared__ __align__(16) us Vt[2][32 * 64];   // [d][key] (src-swizzled)
  __shared__ __align__(16) us Pt[8][16 * 64];   // [wave*2+g][q][key] swz

  int bid = blockIdx.x;
  const us *qT, *kT, *vC; float *pn, *pd; int N, nsp;
  if (bid < nb0) {
    qT = qT0; kT = kT0; vC = vC0; pn = pn0; pd = pd0; N = N0; nsp = nsp0;
  } else {
    bid -= nb0;
    qT = qT1; kT = kT1; vC = vC1; pn = pn1; pd = pd1; N = N1; nsp = nsp1;
  }
  int xcd = bid & 7, slot = bid >> 3;
  int nqb = N >> 7, per = nqb * nsp;
  int qs = slot % per;
  int bh = ((slot / per) << 3) | xcd;    // head pinned to XCD
  int qb = qs / nsp, sp = qs % nsp;
  int b = bh >> 3, h = bh & 7;
  int SK = N / nsp;                      // keys per split
  int tid = threadIdx.x;
  int w = tid >> 6, l = tid & 63;
  int lq = l & 15, l4 = l >> 4;

  // two q-groups per wave: q = qb*128 + g*64 + w*16 + lq
  short8 qfrag[2];
#pragma unroll
  for (int g = 0; g < 2; ++g) {
    const us* qp = qT + ((size_t)(b * N + qb * 128 + g * 64 + w * 16 + lq)) * 256 +
                   h * 32 + l4 * 8;
    qfrag[g] = *(const short8*)qp;
  }

  // --- staging: per-lane swizzled GLOBAL pointers (+ split key offset) ---
  int rK = w * 16 + (l >> 2);
  const us* gK = kT + ((size_t)(b * N + sp * SK + rK)) * 256 + h * 32 +
                 (((l & 3) ^ ((rK >> 1) & 3)) << 3);
  int dV = w * 8 + (l >> 3);
  const us* gV = vC + ((size_t)(b * 256 + h * 32 + dV)) * N + sp * SK +
                 (((l & 7) ^ (dV & 7)) << 3);

  f32x4 acc0[2] = {{0,0,0,0},{0,0,0,0}};
  f32x4 acc1[2] = {{0,0,0,0},{0,0,0,0}};
  f32x4 acc2[2] = {{0,0,0,0},{0,0,0,0}};   // ones-row: denominator per q
  short8 ones;
#pragma unroll
  for (int j = 0; j < 8; ++j) ones[j] = (short)0x3F80;   // bf16 1.0

  // prologue: stage tile 0 into buf 0 (async; first barrier drains)
  glds16(gK, &Kt[0][w * 512]);
  glds16(gV, &Vt[0][w * 512]);

  int nt = SK >> 6, cur = 0;
  for (int t = 0; t < nt; ++t) {
    __syncthreads();                       // drains glds: buf[cur] ready
    if (t + 1 < nt) {                      // issue next tile early (T14)
      glds16(gK + (size_t)(t + 1) * 64 * 256, &Kt[cur ^ 1][w * 512]);
      glds16(gV + (t + 1) * 64, &Vt[cur ^ 1][w * 512]);
    }
    const us* Kb = Kt[cur];
    const us* Vb = Vt[cur];

    // --- QK^T + softmax numerator: K frag read ONCE, used by both q-groups ---
#pragma unroll
    for (int kg = 0; kg < 4; ++kg) {
      int key = kg * 16 + lq;
      short8 a = *(const short8*)&Kb[key * 32 + ((l4 ^ ((key >> 1) & 3)) << 3)];
      f32x4 zero = {0.f, 0.f, 0.f, 0.f};
      int key0 = kg * 16 + l4 * 4;
      int pof = lq * 64 + (((key0 >> 3) ^ (lq & 7)) << 3) + (key0 & 7);
#pragma unroll
      for (int g = 0; g < 2; ++g) {
        __builtin_amdgcn_s_setprio(1);
        f32x4 s = __builtin_amdgcn_mfma_f32_16x16x32_bf16(a, qfrag[g], zero, 0, 0, 0);
        __builtin_amdgcn_s_setprio(0);
        float p0 = exp2_native(s[0]);
        float p1 = exp2_native(s[1]);
        float p2 = exp2_native(s[2]);
        float p3 = exp2_native(s[3]);
        unsigned int r01, r23;
        asm("v_cvt_pk_bf16_f32 %0, %1, %2" : "=v"(r01) : "v"(p0), "v"(p1));
        asm("v_cvt_pk_bf16_f32 %0, %1, %2" : "=v"(r23) : "v"(p2), "v"(p3));
        uint2 pk; pk.x = r01; pk.y = r23;
        *(uint2*)&Pt[w * 2 + g][pof] = pk;
      }
    }

    // --- PV + ones-denominator: V frags read ONCE per kh, used by both groups ---
#pragma unroll
    for (int kh = 0; kh < 2; ++kh) {
      int d0 = lq, d1 = 16 + lq;
      short8 vf0 = *(const short8*)&Vb[d0 * 64 + (((kh * 4 + l4) ^ (d0 & 7)) << 3)];
      short8 vf1 = *(const short8*)&Vb[d1 * 64 + (((kh * 4 + l4) ^ (d1 & 7)) << 3)];
      int pof = lq * 64 + (((kh * 4 + l4) ^ (lq & 7)) << 3);
#pragma unroll
      for (int g = 0; g < 2; ++g) {
        short8 pfr = *(const short8*)&Pt[w * 2 + g][pof];
        __builtin_amdgcn_s_setprio(1);
        acc0[g] = __builtin_amdgcn_mfma_f32_16x16x32_bf16(vf0, pfr, acc0[g], 0, 0, 0);
        acc1[g] = __builtin_amdgcn_mfma_f32_16x16x32_bf16(vf1, pfr, acc1[g], 0, 0, 0);
        acc2[g] = __builtin_amdgcn_mfma_f32_16x16x32_bf16(ones, pfr, acc2[g], 0, 0, 0);
        __builtin_amdgcn_s_setprio(0);
      }
    }
    cur ^= 1;
  }

  // epilogue: f32 partials. pn[s][b][h][d(32)][N] (s stride 512N), pd[s][b][h][N]
  size_t nbase = ((size_t)((sp * 2 + b) * 8 + h)) * 32 * N;
  size_t dbase = ((size_t)((sp * 2 + b) * 8 + h)) * N;
#pragma unroll
  for (int g = 0; g < 2; ++g) {
    int q = qb * 128 + g * 64 + w * 16 + lq;
#pragma unroll
    for (int r = 0; r < 4; ++r) {
      pn[nbase + (size_t)(l4 * 4 + r) * N + q] = acc0[g][r];
      pn[nbase + (size_t)(16 + l4 * 4 + r) * N + q] = acc1[g][r];
    }
    if (l4 == 0) pd[dbase + q] = acc2[g][0];
  }
}

// ---------------------------------------------------------------------------
extern "C" void kernel_launch(void* const* d_in, const int* in_sizes, int n_in,
                              void* d_out, int out_size, void* d_ws, size_t ws_size,
                              hipStream_t stream) {
  const float* high_feat  = (const float*)d_in[0];   // [2,128,64,64]
  const float* low_feat   = (const float*)d_in[1];   // [2,256,32,32]
  const float* q_high_w   = (const float*)d_in[2];
  const float* q_high_b   = (const float*)d_in[3];
  const float* k_high_w   = (const float*)d_in[4];
  const float* k_high_b   = (const float*)d_in[5];
  const float* v_high_w   = (const float*)d_in[6];
  const float* v_high_b   = (const float*)d_in[7];
  const float* q_low_w    = (const float*)d_in[8];
  const float* q_low_b    = (const float*)d_in[9];
  const float* k_low_w    = (const float*)d_in[10];
  const float* k_low_b    = (const float*)d_in[11];
  const float* v_low_w    = (const float*)d_in[12];
  const float* v_low_b    = (const float*)d_in[13];
  const float* out_high_w = (const float*)d_in[14];
  const float* out_high_b = (const float*)d_in[15];
  const float* out_low_w  = (const float*)d_in[16];
  const float* out_low_b  = (const float*)d_in[17];

  const int B = 2, Nh = 4096, Nl = 1024;
  const float qa = 0.17677669529663689f * 1.4426950408889634f;  // scale * log2e

  // workspace carve-up (bytes), ~40 MB
  char* p = (char*)d_ws;
  us* qT    = (us*)p; p += (size_t)2 * 4096 * 256 * 2;  // 4MB
  us* kTb   = (us*)p; p += (size_t)2 * 4096 * 256 * 2;  // 4MB
  us* vCb   = (us*)p; p += (size_t)2 * 256 * 4096 * 2;  // 4MB
  us* klbT  = (us*)p; p += (size_t)2 * 1024 * 256 * 2;  // 1MB
  us* vlb   = (us*)p; p += (size_t)2 * 256 * 1024 * 2;  // 1MB
  us* qTl   = (us*)p; p += (size_t)2 * 1024 * 256 * 2;  // 1MB
  us* kTl   = (us*)p; p += (size_t)2 * 1024 * 256 * 2;  // 1MB
  us* vCl   = (us*)p; p += (size_t)2 * 256 * 1024 * 2;  // 1MB
  float* pnH = (float*)p; p += (size_t)2 * 16 * 32 * 4096 * 4;  // 16.8MB (2 splits)
  float* pdH = (float*)p; p += (size_t)2 * 16 * 4096 * 4;       // 0.5MB
  float* pnL = (float*)p; p += (size_t)2 * 16 * 32 * 1024 * 4;  // 4.2MB (2 splits)
  float* pdL = (float*)p; p += (size_t)2 * 16 * 1024 * 4;       // 0.13MB

  float* out_high = (float*)d_out;             // [2][128][4096]
  float* out_low  = out_high + 2 * 128 * 4096; // [2][256][1024]

  GP z = {nullptr, nullptr, nullptr, nullptr, nullptr, 32, 64, 64, 2, 0, 1, 0.f};

  // 1. ALL input-side GEMMs in ONE launch (k_high/v_high avgpool inline)
  {
    GP s0 = {low_feat,  nullptr, k_low_w,  k_low_b,  klbT, 256, 256, Nl, 0, 0, 1, 1.0f};  // 128
    GP s1 = {low_feat,  nullptr, v_low_w,  v_low_b,  vlb,  256, 256, Nl, 1, 0, 1, 1.0f};  // 128
    GP s2 = {high_feat, nullptr, q_high_w, q_high_b, qT,   128, 256, Nh, 0, 0, 1, qa};    // 512
    GP s3 = {low_feat,  nullptr, q_low_w,  q_low_b,  qTl,  256, 256, Nl, 0, 0, 1, qa};    // 128
    GP s4 = {high_feat, nullptr, k_high_w, k_high_b, kTl,  128, 256, Nl, 0, 3, 1, 1.0f};  // 128
    GP s5 = {high_feat, nullptr, v_high_w, v_high_b, vCl,  128, 256, Nl, 1, 3, 1, 1.0f};  // 128
    gemm_conv<<<1152, 256, 0, stream>>>(s0, s1, s2, s3, s4, s5, 128, 128, 512, 128, 128);
  }
  // 2. both upsamples in ONE launch
  upsample_both<<<2048 + 128, 256, 0, stream>>>(klbT, kTb, vlb, vCb, 2048, B * 256);
  // 3. attention: high split-K x2 (1024 blocks) + low x2 (256), XCD-mapped
  {
    int nb0 = 16 * (Nh / 128) * 2, nb1 = 16 * (Nl / 128) * 2;
    attn_mfma<<<nb0 + nb1, 256, 0, stream>>>(
        qT, kTb, vCb, pnH, pdH, Nh, nb0, 2,
        qTl, kTl, vCl, pnL, pdL, Nl, 2);
  }
  // 4. both output convs in ONE launch, split-K reduce FUSED into staging
  {
    GP s0 = {pnH, pdH, out_high_w, out_high_b, out_high, 256, 128, Nh, 2, 2, 2, 1.0f};  // 256
    GP s1 = {pnL, pdL, out_low_w,  out_low_b,  out_low,  256, 256, Nl, 2, 2, 2, 1.0f};  // 128
    gemm_conv<<<384, 256, 0, stream>>>(s0, s1, z, z, z, z, 256, 128, 0, 0, 0);
  }
}